// Round 10
// baseline (26.518 us; speedup 1.0000x reference)
//
#include <hip/hip_runtime.h>

typedef float float2v __attribute__((ext_vector_type(2)));

#define HW 65536
#define WIMG 256
#define BB 8
#define KK 1024
#define KG 32           // 32x32 control grid, spacing 255/31
#define RECT 8          // 8x8 cp rect covers an 8x8 pixel tile (+24px support)
#define TPB 128         // 2 waves per tile; wave w handles cp rows w*4..w*4+3

__device__ __forceinline__ int rect_origin(int t0) {
    const int n = t0 - 24;
    return (n > 0) ? min((n * (KG - 1) + 254) / 255, KG - RECT) : 0;
}

// Pack tables into batch-pair SoA so wave-uniform s_loads return pk-ready pairs:
// TA[k*4+bp] = (lx[2bp], lx[2bp+1], ly[2bp], ly[2bp+1])
// TB[k*4+bp] = (ax[2bp], ax[2bp+1], ay[2bp], ay[2bp+1])
__global__ __launch_bounds__(256) void pack_pairs(
    const float2* __restrict__ loc2, const float2* __restrict__ alp2,
    float4* __restrict__ TA, float4* __restrict__ TB)
{
    const int id = blockIdx.x * 256 + threadIdx.x;  // 0..4095
    const int k  = id >> 2;
    const int bp = id & 3;
    const float2 l0 = loc2[(2 * bp + 0) * KK + k];
    const float2 l1 = loc2[(2 * bp + 1) * KK + k];
    TA[id] = make_float4(l0.x, l1.x, l0.y, l1.y);
    const float2 a0 = alp2[(2 * bp + 0) * KK + k];
    const float2 a1 = alp2[(2 * bp + 1) * KK + k];
    TB[id] = make_float4(a0.x, a1.x, a0.y, a1.y);
}

__global__ __launch_bounds__(TPB, 4) void rbf_flow_compute(
    const float4* __restrict__ TA,   // (K,4) packed loc pairs
    const float4* __restrict__ TB,   // (K,4) packed alpha pairs
    float* __restrict__ out)         // (B, 2, H, W)
{
    __shared__ float red[16 * 65];   // cross-wave partial sums [comp][lane]

    const int tid  = threadIdx.x;
    const int wv   = __builtin_amdgcn_readfirstlane(tid >> 6); // wave-uniform 0/1
    const int lane = tid & 63;

    const int bx = blockIdx.x & (KG - 1);
    const int by = blockIdx.x >> 5;
    const int x0 = bx * 8;
    const int y0 = by * 8;
    const int r0x = rect_origin(x0);
    const int r0y = rect_origin(y0);

    const float fx = (float)(x0 + (lane & 7));
    const float fy = (float)(y0 + (lane >> 3));

    // control-grid coords, matching np.linspace (f64 mul, then f32 cast)
    float cgx[RECT];
#pragma unroll
    for (int i = 0; i < RECT; ++i)
        cgx[i] = (float)((double)(r0x + i) * (255.0 / 31.0));
    float cgy[4];
#pragma unroll
    for (int i = 0; i < 4; ++i)
        cgy[i] = (float)((double)(r0y + wv * 4 + i) * (255.0 / 31.0));

    float2v accx[4], accy[4];        // [bp] = (batch 2bp, batch 2bp+1)
#pragma unroll
    for (int bp = 0; bp < 4; ++bp) { accx[bp] = (float2v)0.0f; accy[bp] = (float2v)0.0f; }

#pragma unroll
    for (int ky = 0; ky < 4; ++ky) {
        const float cpy = cgy[ky];
        const float dy  = cpy - fy;
        const float dy2 = dy * dy;
        const int krow  = (r0y + wv * 4 + ky) * KG + r0x;   // wave-uniform
#pragma unroll
        for (int kx = 0; kx < RECT; ++kx) {
            const float cpx = cgx[kx];
            const float dx  = cpx - fx;
            const float d2  = fmaf(dx, dx, dy2);
            const float s   = sqrtf(d2);
            const float d   = s * (1.0f / 24.0f);
            // mask folded into clamp: d>=1 -> om=0 -> phi0=gg=0
            const float om  = fmaxf(fmaf(s, -1.0f / 24.0f, 1.0f), 0.0f);
            const float om2 = om * om;
            const float om3 = om2 * om;
            const float om4 = om2 * om2;
            const float phi0 = om4 * fmaf(4.0f, d, 1.0f);
            // gg = phi_r/denom = -20*d*om^3/(576*d+1e-5) ~= -om^3*(20/576)
            // (rel err <=1.3e-5; at d==0 gg is multiplied by dx=dy=0 everywhere)
            const float gg  = om3 * (-20.0f / 576.0f);
            const float gdx = gg * dx;
            const float gdy = gg * dy;
            const float base = fmaf(-gdx, cpx, fmaf(-gdy, cpy, phi0));

            const float2v b2 = {base, base};
            const float2v gx2 = {gdx, gdx};
            const float2v gy2 = {gdy, gdy};

            const float4* __restrict__ pa = TA + (long)(krow + kx) * 4; // uniform
            const float4* __restrict__ pb = TB + (long)(krow + kx) * 4; // uniform
#pragma unroll
            for (int bp = 0; bp < 4; ++bp) {
                const float4 A = pa[bp];          // (lx0,lx1,ly0,ly1) -> s_load
                const float2v lx2 = {A.x, A.y};
                const float2v ly2 = {A.z, A.w};
                const float2v phi2 = __builtin_elementwise_fma(
                    gx2, lx2, __builtin_elementwise_fma(gy2, ly2, b2));
                const float4 Bv = pb[bp];         // (ax0,ax1,ay0,ay1) -> s_load
                const float2v ax2 = {Bv.x, Bv.y};
                const float2v ay2 = {Bv.z, Bv.w};
                accx[bp] = __builtin_elementwise_fma(phi2, ax2, accx[bp]);
                accy[bp] = __builtin_elementwise_fma(phi2, ay2, accy[bp]);
            }
        }
    }

    // ---- cross-wave reduction + store ----
    // component layout: comp = 4*bp + {0: x of b0, 1: x of b1, 2: y of b0, 3: y of b1}
    if (wv == 1) {
#pragma unroll
        for (int bp = 0; bp < 4; ++bp) {
            red[(4 * bp + 0) * 65 + lane] = accx[bp][0];
            red[(4 * bp + 1) * 65 + lane] = accx[bp][1];
            red[(4 * bp + 2) * 65 + lane] = accy[bp][0];
            red[(4 * bp + 3) * 65 + lane] = accy[bp][1];
        }
    }
    __syncthreads();
    if (wv == 0) {
        const int pix = (y0 + (lane >> 3)) * WIMG + x0 + (lane & 7);
#pragma unroll
        for (int bp = 0; bp < 4; ++bp) {
            const float rx0 = red[(4 * bp + 0) * 65 + lane];
            const float rx1 = red[(4 * bp + 1) * 65 + lane];
            const float ry0 = red[(4 * bp + 2) * 65 + lane];
            const float ry1 = red[(4 * bp + 3) * 65 + lane];
            const int b0 = 2 * bp, b1 = 2 * bp + 1;
            out[(2 * b0 + 0) * HW + pix] = accx[bp][0] + rx0;
            out[(2 * b0 + 1) * HW + pix] = accy[bp][0] + ry0;
            out[(2 * b1 + 0) * HW + pix] = accx[bp][1] + rx1;
            out[(2 * b1 + 1) * HW + pix] = accy[bp][1] + ry1;
        }
    }
}

extern "C" void kernel_launch(void* const* d_in, const int* in_sizes, int n_in,
                              void* d_out, int out_size, void* d_ws, size_t ws_size,
                              hipStream_t stream) {
    const float* cpoint_loc = (const float*)d_in[0];
    const float* alpha      = (const float*)d_in[1];
    float* out = (float*)d_out;

    float4* TA = (float4*)d_ws;          // 64 KB
    float4* TB = TA + KK * 4;            // 64 KB

    pack_pairs<<<KK * 4 / 256, 256, 0, stream>>>(
        (const float2*)cpoint_loc, (const float2*)alpha, TA, TB);

    rbf_flow_compute<<<KG * KG, TPB, 0, stream>>>(TA, TB, out);
}

// Round 11
// 13.474 us; speedup vs baseline: 1.9681x; 1.9681x over previous
//
#include <hip/hip_runtime.h>

typedef float f32x4 __attribute__((ext_vector_type(4)));
typedef short bf16x8 __attribute__((ext_vector_type(8)));

#define HW 65536
#define WIMG 256
#define BB 8
#define KK 1024
#define KG 32           // 32x32 control grid, spacing 255/31
#define RECT 8          // 8x8 cp rect covers an 8x8 pixel tile (+24px support)
#define TPB 256         // 4 waves per tile

__device__ __forceinline__ int rect_origin(int t0) {
    const int n = t0 - 24;
    return (n > 0) ? min((n * (KG - 1) + 254) / 255, KG - RECT) : 0;
}
// round-to-nearest-even f32 -> bf16 (no NaN handling needed here)
__device__ __forceinline__ unsigned bfr(float x) {
    const unsigned u = __float_as_uint(x);
    return (u + 0x7FFFu + ((u >> 16) & 1u)) >> 16;
}
__device__ __forceinline__ unsigned pk2(float lo, float hi) {
    return bfr(lo) | (bfr(hi) << 16);
}
__device__ __forceinline__ float cgrid(int i) {   // np.linspace(0,255,32)[i]
    return (float)((double)i * (255.0 / 31.0));
}

__global__ __launch_bounds__(TPB) void rbf_mfma(
    const float2* __restrict__ loc2,   // cpoint_loc (B,K,2)
    const float2* __restrict__ alp2,   // alpha      (B,K,2)
    float* __restrict__ out)           // (B,2,H,W)
{
    // LDS map: [0,8192) Ut: 16 rows x 512B (K'=256 bf16, swizzled)
    //          [8192,40960) G: 64 rows x 512B (swizzled); LT overlaps G before
    //          G is written (barrier-separated).
    __shared__ uint4 smem4[2560];                 // 40960 B -> 4 blocks/CU
    char* const base = (char*)smem4;
    float4* const LT = (float4*)(base + 8192);    // 512 x float4 = 8 KB

    const int tid = threadIdx.x;
    const int bx = blockIdx.x & (KG - 1);
    const int by = blockIdx.x >> 5;
    const int x0 = bx * 8, y0 = by * 8;
    const int r0x = rect_origin(x0), r0y = rect_origin(y0);

    // ---- phase A: stage LT rect: 512 entries (ent=sy*8+sx, b) ----
#pragma unroll
    for (int j = 0; j < 2; ++j) {
        const int e   = tid + j * TPB;            // 0..511
        const int b   = e & 7;
        const int ent = e >> 3;
        const int k   = (r0y + (ent >> 3)) * KG + r0x + (ent & 7);
        const float2 l = loc2[b * KK + k];
        const float2 a = alp2[b * KK + k];
        LT[e] = make_float4(l.x, l.y, a.x, a.y);
    }
    __syncthreads();

    // ---- phase B: build Ut[n][k], k=4e+{0,1,2,3} = (a, (lx-cpx)a, (ly-cpy)a, 0)
    {
        const int n = tid >> 4;                   // 0..15 (= 2b+c plane)
        const int q = tid & 15;
        const int b = n >> 1;
        const int c = n & 1;
#pragma unroll
        for (int i = 0; i < 4; ++i) {
            const int e = q * 4 + i;              // cp within rect 0..63
            const float4 t = LT[e * 8 + b];
            const float a  = c ? t.w : t.z;       // ay : ax
            const float cpx = cgrid(r0x + (e & 7));
            const float cpy = cgrid(r0y + (e >> 3));
            const float u2 = (t.x - cpx) * a;
            const float u3 = (t.y - cpy) * a;
            const unsigned d0 = pk2(a, u2);
            const unsigned d1 = pk2(u3, 0.0f);
            const int addr = (n * 512 + 8 * e) ^ ((n & 7) << 4);
            *(uint2*)(base + addr) = make_uint2(d0, d1);
        }
    }
    __syncthreads();

    // ---- phase C: geometry -> G[px][k] bf16 (overwrites LT region) ----
    const int wv   = tid >> 6;                    // 0..3
    const int lane = tid & 63;
    {
        const int px = lane;                      // 0..63
        const float fx = (float)(x0 + (px & 7));
        const float fy = (float)(y0 + (px >> 3));
        float cgx[8];
#pragma unroll
        for (int i = 0; i < 8; ++i) cgx[i] = cgrid(r0x + i);
        const float cpy0 = cgrid(r0y + 2 * wv);
        const float cpy1 = cgrid(r0y + 2 * wv + 1);
#pragma unroll
        for (int p = 0; p < 8; ++p) {             // pairs of cps e0,e0+1
            const int e0 = wv * 16 + 2 * p;
            unsigned d[4];
#pragma unroll
            for (int h = 0; h < 2; ++h) {
                const int e = e0 + h;
                const float cpy = (e >> 3) == 2 * wv ? cpy0 : cpy1;
                const float cpx = cgx[e & 7];
                const float dx = cpx - fx;
                const float dy = cpy - fy;
                const float d2 = fmaf(dx, dx, dy * dy);
                const float s  = sqrtf(d2);
                const float dd = s * (1.0f / 24.0f);
                const float om = fmaxf(fmaf(s, -1.0f / 24.0f, 1.0f), 0.0f);
                const float om2 = om * om;
                const float om3 = om2 * om;
                const float phi0 = om2 * om2 * fmaf(4.0f, dd, 1.0f);
                const float gg  = om3 * (-20.0f / 576.0f); // phi_r/denom (validated r10)
                const float gdx = gg * dx;
                const float gdy = gg * dy;
                d[2 * h]     = pk2(phi0, gdx);
                d[2 * h + 1] = pk2(gdy, 0.0f);
            }
            const int addr = (px * 512 + 8 * e0) ^ ((px & 7) << 4);
            *(uint4*)(base + 8192 + addr) = make_uint4(d[0], d[1], d[2], d[3]);
        }
    }
    __syncthreads();

    // ---- phase D: MFMA. wave wv owns m-tile wv (px rows 16wv..16wv+15) ----
    f32x4 acc = {0.f, 0.f, 0.f, 0.f};
    {
        const int arow = wv * 16 + (lane & 15);   // global px row
        const int brow = lane & 15;               // n
        const int chunk = (lane >> 4) * 16;       // k-chunk byte offset
#pragma unroll
        for (int kk = 0; kk < 8; ++kk) {
            const int ko = kk * 64 + chunk;
            const int aaddr = (arow * 512 + ko) ^ ((arow & 7) << 4);
            const int baddr = (brow * 512 + ko) ^ ((brow & 7) << 4);
            const bf16x8 av = *(const bf16x8*)(base + 8192 + aaddr);
            const bf16x8 bv = *(const bf16x8*)(base + baddr);
            acc = __builtin_amdgcn_mfma_f32_16x16x32_bf16(av, bv, acc, 0, 0, 0);
        }
    }

    // ---- phase E: store. C: col=lane&15 (=n), row=(lane>>4)*4+reg ----
    {
        const int n = lane & 15;
        const int rb = (lane >> 4) * 4;
#pragma unroll
        for (int r = 0; r < 4; ++r) {
            const int px = wv * 16 + rb + r;
            const int pix = (y0 + (px >> 3)) * WIMG + x0 + (px & 7);
            out[n * HW + pix] = acc[r];
        }
    }
}

extern "C" void kernel_launch(void* const* d_in, const int* in_sizes, int n_in,
                              void* d_out, int out_size, void* d_ws, size_t ws_size,
                              hipStream_t stream) {
    const float2* cpoint_loc = (const float2*)d_in[0];
    const float2* alpha      = (const float2*)d_in[1];
    float* out = (float*)d_out;

    rbf_mfma<<<KG * KG, TPB, 0, stream>>>(cpoint_loc, alpha, out);
}

// Round 12
// 11.375 us; speedup vs baseline: 2.3313x; 1.1845x over previous
//
#include <hip/hip_runtime.h>

typedef float f32x4 __attribute__((ext_vector_type(4)));
typedef short bf16x8 __attribute__((ext_vector_type(8)));

#define HW 65536
#define WIMG 256
#define BB 8
#define KK 1024
#define KG 32           // 32x32 control grid, spacing 255/31
#define RECT 8          // 8x8 cp rect covers an 8x8 pixel tile (+24px support)
#define TPB 256         // 4 waves per tile

__device__ __forceinline__ int rect_origin(int t0) {
    const int n = t0 - 24;
    return (n > 0) ? min((n * (KG - 1) + 254) / 255, KG - RECT) : 0;
}
// hardware packed f32x2 -> bf16x2 (RNE), T12 recipe
__device__ __forceinline__ unsigned pk2(float lo, float hi) {
    unsigned r;
    asm("v_cvt_pk_bf16_f32 %0, %1, %2" : "=v"(r) : "v"(lo), "v"(hi));
    return r;
}
__device__ __forceinline__ float cgrid(int i) {   // np.linspace(0,255,32)[i]
    return (float)((double)i * (255.0 / 31.0));
}

__global__ __launch_bounds__(TPB, 8) void rbf_mfma(
    const float2* __restrict__ loc2,   // cpoint_loc (B,K,2)
    const float2* __restrict__ alp2,   // alpha      (B,K,2)
    float* __restrict__ out)           // (B,2,H,W)
{
    __shared__ uint4 Ut4[512];          // 8 KB: Ut, 16 rows x 512 B (swizzled)
    char* const base = (char*)Ut4;

    const int tid = threadIdx.x;
    const int bx = blockIdx.x & (KG - 1);
    const int by = blockIdx.x >> 5;
    const int x0 = bx * 8, y0 = by * 8;
    const int r0x = rect_origin(x0), r0y = rect_origin(y0);

    // ---- build Ut[n][k] straight from global tables (L2-hot gathers) ----
    // thread (b = tid&7, q = tid>>3) handles cps e = 2q, 2q+1 for BOTH
    // output components n = 2b, 2b+1. One 16B LDS write per row.
    {
        const int b   = tid & 7;
        const int q   = tid >> 3;        // 0..31
        const int gy  = q >> 2;          // cp row in rect
        const int gx0 = (q & 3) * 2;     // cp col of e=2q
        const int kbase = b * KK + (r0y + gy) * KG + r0x + gx0;
        const float2 l0 = loc2[kbase];
        const float2 l1 = loc2[kbase + 1];
        const float2 a0 = alp2[kbase];
        const float2 a1 = alp2[kbase + 1];
        const float cpy  = cgrid(r0y + gy);
        const float cpx0 = cgrid(r0x + gx0);
        const float cpx1 = cgrid(r0x + gx0 + 1);
        const float dlx0 = l0.x - cpx0, dly0 = l0.y - cpy;
        const float dlx1 = l1.x - cpx1, dly1 = l1.y - cpy;
        const int n0 = 2 * b, n1 = 2 * b + 1;
        const uint4 w0 = make_uint4(                 // c=0 plane: ax
            pk2(a0.x, dlx0 * a0.x), pk2(dly0 * a0.x, 0.0f),
            pk2(a1.x, dlx1 * a1.x), pk2(dly1 * a1.x, 0.0f));
        const uint4 w1 = make_uint4(                 // c=1 plane: ay
            pk2(a0.y, dlx0 * a0.y), pk2(dly0 * a0.y, 0.0f),
            pk2(a1.y, dlx1 * a1.y), pk2(dly1 * a1.y, 0.0f));
        *(uint4*)(base + ((n0 * 512 + 16 * q) ^ ((n0 & 7) << 4))) = w0;
        *(uint4*)(base + ((n1 * 512 + 16 * q) ^ ((n1 & 7) << 4))) = w1;
    }
    __syncthreads();

    // ---- fused geometry -> register A-fragment -> MFMA ----
    const int wv   = tid >> 6;           // m-tile 0..3
    const int lane = tid & 63;
    const int row  = lane & 15;          // A row within m-tile / B col (n)
    const int ch   = lane >> 4;          // k-chunk 0..3
    const float fx = (float)(x0 + (lane & 7));
    const float fy = (float)(y0 + wv * 2 + ((lane >> 3) & 1));
    const float cpx0 = cgrid(r0x + 2 * ch);
    const float cpx1 = cgrid(r0x + 2 * ch + 1);
    const float dx0 = cpx0 - fx;
    const float dx1 = cpx1 - fx;

    f32x4 acc = {0.f, 0.f, 0.f, 0.f};
#pragma unroll
    for (int kk = 0; kk < 8; ++kk) {     // cp rows of the rect
        const float cpy = cgrid(r0y + kk);
        const float dy  = cpy - fy;
        const float dy2 = dy * dy;
        // cp A (e = kk*8 + 2ch)
        const float d2a  = fmaf(dx0, dx0, dy2);
        const float sa   = sqrtf(d2a);
        const float oma  = fmaxf(fmaf(sa, -1.0f / 24.0f, 1.0f), 0.0f);
        const float oma2 = oma * oma;
        const float phia = (oma2 * oma2) * fmaf(sa, 1.0f / 6.0f, 1.0f);
        const float gga  = (oma2 * oma) * (-20.0f / 576.0f); // phi_r/denom (r10-validated)
        // cp B (e+1)
        const float d2b  = fmaf(dx1, dx1, dy2);
        const float sb   = sqrtf(d2b);
        const float omb  = fmaxf(fmaf(sb, -1.0f / 24.0f, 1.0f), 0.0f);
        const float omb2 = omb * omb;
        const float phib = (omb2 * omb2) * fmaf(sb, 1.0f / 6.0f, 1.0f);
        const float ggb  = (omb2 * omb) * (-20.0f / 576.0f);

        const uint4 a4 = make_uint4(
            pk2(phia, gga * dx0), pk2(gga * dy, 0.0f),
            pk2(phib, ggb * dx1), pk2(ggb * dy, 0.0f));
        const bf16x8 av = __builtin_bit_cast(bf16x8, a4);
        const bf16x8 bv = *(const bf16x8*)(base +
            ((row * 512 + kk * 64 + ch * 16) ^ ((row & 7) << 4)));
        acc = __builtin_amdgcn_mfma_f32_16x16x32_bf16(av, bv, acc, 0, 0, 0);
    }

    // ---- store. C/D layout: col = lane&15 (= n), row = ch*4 + r ----
    {
        const int n  = lane & 15;
        const int rb = ch * 4;
#pragma unroll
        for (int r = 0; r < 4; ++r) {
            const int px = wv * 16 + rb + r;
            const int pix = (y0 + (px >> 3)) * WIMG + x0 + (px & 7);
            out[n * HW + pix] = acc[r];
        }
    }
}

extern "C" void kernel_launch(void* const* d_in, const int* in_sizes, int n_in,
                              void* d_out, int out_size, void* d_ws, size_t ws_size,
                              hipStream_t stream) {
    const float2* cpoint_loc = (const float2*)d_in[0];
    const float2* alpha      = (const float2*)d_in[1];
    float* out = (float*)d_out;

    rbf_mfma<<<KG * KG, TPB, 0, stream>>>(cpoint_loc, alpha, out);
}